// Round 1
// baseline (1805.799 us; speedup 1.0000x reference)
//
#include <hip/hip_runtime.h>
#include <hip/hip_bf16.h>
#include <math.h>

#define LN_EPS 1e-5f
#define EPSA 1e-8f
#define SCALE 0.0625f   // 256^-0.5

// ---------- helpers ----------
__device__ inline void bf2x(unsigned int u, float& a, float& b) {
    union { unsigned int i; float f; } lo, hi;
    lo.i = u << 16; hi.i = u & 0xffff0000u;
    a = lo.f; b = hi.f;
}
__device__ inline float sigmoidf_(float x) { return 1.0f / (1.0f + expf(-x)); }

// ---------- K1: per-row mean/rstd of x (131072 rows x 256) ----------
__global__ __launch_bounds__(256) void row_stats(const float* __restrict__ x,
                                                 float* __restrict__ stats) {
    int w = threadIdx.x >> 6;
    int lane = threadIdx.x & 63;
    int r = blockIdx.x * 4 + w;
    const float4 xv = ((const float4*)(x + (size_t)r * 256))[lane];
    float s = xv.x + xv.y + xv.z + xv.w;
    float s2 = xv.x*xv.x + xv.y*xv.y + xv.z*xv.z + xv.w*xv.w;
    for (int off = 32; off > 0; off >>= 1) {
        s  += __shfl_down(s, off);
        s2 += __shfl_down(s2, off);
    }
    if (lane == 0) {
        float m = s * (1.0f/256.0f);
        float v = s2 * (1.0f/256.0f) - m * m;
        stats[2*r]   = m;
        stats[2*r+1] = rsqrtf(v + LN_EPS);
    }
}

// ---------- K2: pack Wk^T|Wv^T into Wc[256][512] ----------
__global__ __launch_bounds__(256) void pack_w(const float* __restrict__ Wk,
                                              const float* __restrict__ Wv,
                                              float* __restrict__ Wc) {
    int idx = blockIdx.x * 256 + threadIdx.x;   // i*512 + j, 131072 total
    int i = idx >> 9, j = idx & 511;
    Wc[idx] = (j < 256) ? Wk[j*256 + i] : Wv[(j-256)*256 + i];
}

// ---------- K3: fused LN + GEMM -> k,v (bf16) ----------
// C[131072 x 512] = LN(x) @ Wc ; tiles 64x64x64, f32 VALU
__global__ __launch_bounds__(256) void gemm_kv(const float* __restrict__ x,
                                               const float* __restrict__ stats,
                                               const float* __restrict__ nx_g,
                                               const float* __restrict__ nx_b,
                                               const float* __restrict__ Wc,
                                               __hip_bfloat16* __restrict__ kp,
                                               __hip_bfloat16* __restrict__ vp) {
    __shared__ float As[64][68];
    __shared__ float Bs[64][68];
    int bm = blockIdx.x;          // 0..2047
    int bn = blockIdx.y;          // 0..7
    int t = threadIdx.x;
    int row0 = bm * 64, col0 = bn * 64;
    int tm = t >> 4, tn = t & 15;
    float acc[4][4] = {};
    for (int kt = 0; kt < 256; kt += 64) {
        #pragma unroll
        for (int j = 0; j < 16; ++j) {
            int li = t + 256*j;
            int rr = li >> 6, cc = li & 63;
            int r = row0 + rr, c = kt + cc;
            float xv = x[(size_t)r*256 + c];
            As[rr][cc] = (xv - stats[2*r]) * stats[2*r+1] * nx_g[c] + nx_b[c];
        }
        #pragma unroll
        for (int j = 0; j < 16; ++j) {
            int li = t + 256*j;
            int rr = li >> 6, cc = li & 63;
            Bs[rr][cc] = Wc[(kt + rr)*512 + col0 + cc];
        }
        __syncthreads();
        for (int kk = 0; kk < 64; ++kk) {
            float a0 = As[tm*4+0][kk], a1 = As[tm*4+1][kk];
            float a2 = As[tm*4+2][kk], a3 = As[tm*4+3][kk];
            float b0 = Bs[kk][tn*4+0], b1 = Bs[kk][tn*4+1];
            float b2 = Bs[kk][tn*4+2], b3 = Bs[kk][tn*4+3];
            acc[0][0] += a0*b0; acc[0][1] += a0*b1; acc[0][2] += a0*b2; acc[0][3] += a0*b3;
            acc[1][0] += a1*b0; acc[1][1] += a1*b1; acc[1][2] += a1*b2; acc[1][3] += a1*b3;
            acc[2][0] += a2*b0; acc[2][1] += a2*b1; acc[2][2] += a2*b2; acc[2][3] += a2*b3;
            acc[3][0] += a3*b0; acc[3][1] += a3*b1; acc[3][2] += a3*b2; acc[3][3] += a3*b3;
        }
        __syncthreads();
    }
    #pragma unroll
    for (int i = 0; i < 4; ++i)
        #pragma unroll
        for (int j = 0; j < 4; ++j) {
            int r = row0 + tm*4 + i, c = col0 + tn*4 + j;
            __hip_bfloat16 hv = __float2bfloat16(acc[i][j]);
            if (c < 256) kp[(size_t)r*256 + c] = hv;
            else         vp[(size_t)r*256 + (c - 256)] = hv;
        }
}

// ---------- K4: slots init ----------
__global__ __launch_bounds__(256) void slots_init(const float* __restrict__ noise,
                                                  const float* __restrict__ mu,
                                                  const float* __restrict__ logsigma,
                                                  float* __restrict__ slots) {
    int i = blockIdx.x * 256 + threadIdx.x;   // 65536
    int d = i & 255;
    slots[i] = mu[d] + expf(logsigma[d]) * noise[i];
}

// ---------- K5: LN(slots) + q projection (one block per b) ----------
__global__ __launch_bounds__(256) void qproj(const float* __restrict__ slots,
                                             const float* __restrict__ ns_g,
                                             const float* __restrict__ ns_b,
                                             const float* __restrict__ Wq,
                                             float* __restrict__ q) {
    int b = blockIdx.x, t = threadIdx.x;
    __shared__ float sn[256];
    __shared__ float red[8];
    for (int r = 0; r < 8; ++r) {
        int row = b*8 + r;
        float v = slots[row*256 + t];
        float s = v, s2 = v*v;
        for (int off = 32; off > 0; off >>= 1) {
            s  += __shfl_down(s, off);
            s2 += __shfl_down(s2, off);
        }
        if ((t & 63) == 0) { red[t>>6] = s; red[4 + (t>>6)] = s2; }
        __syncthreads();
        float S  = red[0]+red[1]+red[2]+red[3];
        float S2 = red[4]+red[5]+red[6]+red[7];
        float m = S * (1.0f/256.0f);
        float var = S2 * (1.0f/256.0f) - m*m;
        float rs = rsqrtf(var + LN_EPS);
        sn[t] = (v - m) * rs * ns_g[t] + ns_b[t];
        __syncthreads();
        float acc = 0.0f;
        const float4* wrow = (const float4*)(Wq + t*256);
        #pragma unroll 8
        for (int i = 0; i < 64; ++i) {
            float4 w = wrow[i];
            acc += w.x*sn[4*i] + w.y*sn[4*i+1] + w.z*sn[4*i+2] + w.w*sn[4*i+3];
        }
        q[row*256 + t] = acc;
        __syncthreads();
    }
}

// ---------- K6: logits + softmax(K) + attn out + partial updates ----------
__global__ __launch_bounds__(256) void attn_updates(const __hip_bfloat16* __restrict__ kp,
                                                    const __hip_bfloat16* __restrict__ vp,
                                                    const float* __restrict__ q,
                                                    float* __restrict__ attn_out,
                                                    float* __restrict__ partial) {
    int b = blockIdx.x >> 4, ch = blockIdx.x & 15, t = threadIdx.x;
    __shared__ float qs[8][256];
    __shared__ float as[8][256];
    #pragma unroll
    for (int j = 0; j < 8; ++j) qs[j][t] = q[(b*8 + j)*256 + t];
    __syncthreads();

    int n = ch*256 + t;
    const uint4* k4 = (const uint4*)(kp + ((size_t)b*4096 + n)*256);
    float lg[8] = {0,0,0,0,0,0,0,0};
    for (int i = 0; i < 32; ++i) {
        uint4 u = k4[i];
        float f[8];
        bf2x(u.x, f[0], f[1]); bf2x(u.y, f[2], f[3]);
        bf2x(u.z, f[4], f[5]); bf2x(u.w, f[6], f[7]);
        int d0 = i*8;
        #pragma unroll
        for (int kk = 0; kk < 8; ++kk) {
            float a = 0.0f;
            #pragma unroll
            for (int j = 0; j < 8; ++j) a += f[j] * qs[kk][d0 + j];
            lg[kk] += a;
        }
    }
    float mx = -1e30f;
    #pragma unroll
    for (int kk = 0; kk < 8; ++kk) { lg[kk] *= SCALE; mx = fmaxf(mx, lg[kk]); }
    float sum = 0.0f;
    #pragma unroll
    for (int kk = 0; kk < 8; ++kk) { lg[kk] = expf(lg[kk] - mx); sum += lg[kk]; }
    float inv = 1.0f / sum;
    const float renorm = 1.0f / (1.0f + 8.0f*EPSA);
    #pragma unroll
    for (int kk = 0; kk < 8; ++kk) {
        float a = (lg[kk]*inv + EPSA) * renorm;
        as[kk][t] = a;
        attn_out[((size_t)(b*8 + kk))*4096 + n] = a;
    }
    __syncthreads();

    int kk = t >> 5, dg = t & 31;
    float acc[8] = {0,0,0,0,0,0,0,0};
    const uint4* v4 = (const uint4*)(vp + ((size_t)b*4096 + ch*256)*256);
    for (int nn = 0; nn < 256; ++nn) {
        float a = as[kk][nn];
        uint4 u = v4[nn*32 + dg];
        float f[8];
        bf2x(u.x, f[0], f[1]); bf2x(u.y, f[2], f[3]);
        bf2x(u.z, f[4], f[5]); bf2x(u.w, f[6], f[7]);
        #pragma unroll
        for (int j = 0; j < 8; ++j) acc[j] += a * f[j];
    }
    float* p = partial + (((size_t)(b*16 + ch)*8 + kk)*256) + dg*8;
    #pragma unroll
    for (int j = 0; j < 8; ++j) p[j] = acc[j];
}

// ---------- K7: reduce partials + GRU cell -> hprime ----------
__global__ __launch_bounds__(256) void gru(const float* __restrict__ partial,
                                           const float* __restrict__ slots,
                                           const float* __restrict__ W_ih,
                                           const float* __restrict__ W_hh,
                                           const float* __restrict__ b_ih,
                                           const float* __restrict__ b_hh,
                                           float* __restrict__ hprime) {
    int r = blockIdx.x, t = threadIdx.x;
    int b = r >> 3, k = r & 7;
    __shared__ float u_s[256], h_s[256];
    float u = 0.0f;
    #pragma unroll
    for (int ch = 0; ch < 16; ++ch)
        u += partial[(((size_t)(b*16 + ch)*8 + k)*256) + t];
    u_s[t] = u;
    h_s[t] = slots[r*256 + t];
    __syncthreads();

    float gi_r = b_ih[t], gi_z = b_ih[256 + t], gi_n = b_ih[512 + t];
    float gh_r = b_hh[t], gh_z = b_hh[256 + t], gh_n = b_hh[512 + t];
    const float4* wir = (const float4*)(W_ih + (size_t)t*256);
    const float4* wiz = (const float4*)(W_ih + (size_t)(256 + t)*256);
    const float4* win = (const float4*)(W_ih + (size_t)(512 + t)*256);
    const float4* whr = (const float4*)(W_hh + (size_t)t*256);
    const float4* whz = (const float4*)(W_hh + (size_t)(256 + t)*256);
    const float4* whn = (const float4*)(W_hh + (size_t)(512 + t)*256);
    #pragma unroll 4
    for (int i = 0; i < 64; ++i) {
        float u0 = u_s[4*i], u1 = u_s[4*i+1], u2 = u_s[4*i+2], u3 = u_s[4*i+3];
        float h0 = h_s[4*i], h1 = h_s[4*i+1], h2 = h_s[4*i+2], h3 = h_s[4*i+3];
        float4 w;
        w = wir[i]; gi_r += w.x*u0 + w.y*u1 + w.z*u2 + w.w*u3;
        w = wiz[i]; gi_z += w.x*u0 + w.y*u1 + w.z*u2 + w.w*u3;
        w = win[i]; gi_n += w.x*u0 + w.y*u1 + w.z*u2 + w.w*u3;
        w = whr[i]; gh_r += w.x*h0 + w.y*h1 + w.z*h2 + w.w*h3;
        w = whz[i]; gh_z += w.x*h0 + w.y*h1 + w.z*h2 + w.w*h3;
        w = whn[i]; gh_n += w.x*h0 + w.y*h1 + w.z*h2 + w.w*h3;
    }
    float rg = sigmoidf_(gi_r + gh_r);
    float zg = sigmoidf_(gi_z + gh_z);
    float ng = tanhf(gi_n + rg * gh_n);
    hprime[r*256 + t] = (1.0f - zg)*ng + zg*h_s[t];
}

// ---------- K8: LN + MLP (GELU exact) + residual -> slots ----------
__global__ __launch_bounds__(256) void mlp(const float* __restrict__ hprime,
                                           const float* __restrict__ mlp_g,
                                           const float* __restrict__ mlp_b,
                                           const float* __restrict__ W1,
                                           const float* __restrict__ b1,
                                           const float* __restrict__ W2,
                                           const float* __restrict__ b2,
                                           float* __restrict__ slots,
                                           float* __restrict__ out_slots,
                                           int last) {
    int r = blockIdx.x, t = threadIdx.x;
    __shared__ float hn[256];
    __shared__ float m1[512];
    __shared__ float red[8];
    float h = hprime[r*256 + t];
    float s = h, s2 = h*h;
    for (int off = 32; off > 0; off >>= 1) {
        s  += __shfl_down(s, off);
        s2 += __shfl_down(s2, off);
    }
    if ((t & 63) == 0) { red[t>>6] = s; red[4 + (t>>6)] = s2; }
    __syncthreads();
    float S  = red[0]+red[1]+red[2]+red[3];
    float S2 = red[4]+red[5]+red[6]+red[7];
    float m = S * (1.0f/256.0f);
    float var = S2 * (1.0f/256.0f) - m*m;
    float rs = rsqrtf(var + LN_EPS);
    hn[t] = (h - m) * rs * mlp_g[t] + mlp_b[t];
    __syncthreads();

    #pragma unroll
    for (int jj = 0; jj < 2; ++jj) {
        int j = t + jj*256;
        float acc = b1[j];
        const float4* w = (const float4*)(W1 + (size_t)j*256);
        #pragma unroll 8
        for (int i = 0; i < 64; ++i) {
            float4 wv = w[i];
            acc += wv.x*hn[4*i] + wv.y*hn[4*i+1] + wv.z*hn[4*i+2] + wv.w*hn[4*i+3];
        }
        m1[j] = 0.5f * acc * (1.0f + erff(acc * 0.70710678118654752f));
    }
    __syncthreads();

    float acc = b2[t];
    const float4* w2 = (const float4*)(W2 + (size_t)t*512);
    #pragma unroll 8
    for (int i = 0; i < 128; ++i) {
        float4 wv = w2[i];
        acc += wv.x*m1[4*i] + wv.y*m1[4*i+1] + wv.z*m1[4*i+2] + wv.w*m1[4*i+3];
    }
    float res = h + acc;
    slots[r*256 + t] = res;
    if (last) out_slots[r*256 + t] = res;
}

// ---------- launch ----------
extern "C" void kernel_launch(void* const* d_in, const int* in_sizes, int n_in,
                              void* d_out, int out_size, void* d_ws, size_t ws_size,
                              hipStream_t stream) {
    const float* x        = (const float*)d_in[0];
    const float* noise    = (const float*)d_in[1];
    const float* nx_g     = (const float*)d_in[2];
    const float* nx_b     = (const float*)d_in[3];
    const float* ns_g     = (const float*)d_in[4];
    const float* ns_b     = (const float*)d_in[5];
    const float* mu       = (const float*)d_in[6];
    const float* logsigma = (const float*)d_in[7];
    const float* Wq       = (const float*)d_in[8];
    const float* Wk       = (const float*)d_in[9];
    const float* Wv       = (const float*)d_in[10];
    const float* W_ih     = (const float*)d_in[11];
    const float* W_hh     = (const float*)d_in[12];
    const float* b_ih     = (const float*)d_in[13];
    const float* b_hh     = (const float*)d_in[14];
    const float* mlp_g    = (const float*)d_in[15];
    const float* mlp_b    = (const float*)d_in[16];
    const float* W1       = (const float*)d_in[17];
    const float* b1       = (const float*)d_in[18];
    const float* W2       = (const float*)d_in[19];
    const float* b2       = (const float*)d_in[20];

    float* out_slots = (float*)d_out;            // [32][8][256]
    float* out_attn  = (float*)d_out + 65536;    // [32][8][4096]

    char* ws = (char*)d_ws;
    float* stats = (float*)ws;                               // 131072*2 f32 = 1 MB
    float* Wc    = stats + 262144;                           // 256*512 f32 = 512 KB
    __hip_bfloat16* kp = (__hip_bfloat16*)(Wc + 131072);     // 33.5M bf16 = 67 MB
    __hip_bfloat16* vp = kp + (size_t)33554432;              // 67 MB
    float* slots  = (float*)(vp + (size_t)33554432);         // 65536 f32
    float* qbuf   = slots + 65536;                           // 65536 f32
    float* partial= qbuf + 65536;                            // 32*16*8*256 f32 = 4 MB
    float* hprime = partial + 1048576;                       // 65536 f32

    row_stats<<<32768, 256, 0, stream>>>(x, stats);
    pack_w<<<512, 256, 0, stream>>>(Wk, Wv, Wc);
    dim3 g2(2048, 8);
    gemm_kv<<<g2, 256, 0, stream>>>(x, stats, nx_g, nx_b, Wc, kp, vp);
    slots_init<<<256, 256, 0, stream>>>(noise, mu, logsigma, slots);

    for (int it = 0; it < 3; ++it) {
        qproj<<<32, 256, 0, stream>>>(slots, ns_g, ns_b, Wq, qbuf);
        attn_updates<<<512, 256, 0, stream>>>(kp, vp, qbuf, out_attn, partial);
        gru<<<256, 256, 0, stream>>>(partial, slots, W_ih, W_hh, b_ih, b_hh, hprime);
        mlp<<<256, 256, 0, stream>>>(hprime, mlp_g, mlp_b, W1, b1, W2, b2,
                                     slots, out_slots, it == 2);
    }
}

// Round 2
// 811.500 us; speedup vs baseline: 2.2253x; 2.2253x over previous
//
#include <hip/hip_runtime.h>
#include <hip/hip_bf16.h>
#include <math.h>

#define LN_EPS 1e-5f
#define EPSA 1e-8f
#define SCALE 0.0625f   // 256^-0.5

typedef __attribute__((ext_vector_type(8))) short short8;
typedef __attribute__((ext_vector_type(4))) float f32x4;

// ---------- helpers ----------
__device__ inline void bf2x(unsigned int u, float& a, float& b) {
    union { unsigned int i; float f; } lo, hi;
    lo.i = u << 16; hi.i = u & 0xffff0000u;
    a = lo.f; b = hi.f;
}
__device__ inline float sigmoidf_(float x) { return 1.0f / (1.0f + expf(-x)); }
__device__ inline unsigned short f2bf(float f) {
    union { float f; unsigned int u; } v; v.f = f;
    unsigned int r = v.u + 0x7fffu + ((v.u >> 16) & 1u);   // RNE
    return (unsigned short)(r >> 16);
}

// ---------- K1: per-row mean/rstd of x (131072 rows x 256) ----------
__global__ __launch_bounds__(256) void row_stats(const float* __restrict__ x,
                                                 float* __restrict__ stats) {
    int w = threadIdx.x >> 6;
    int lane = threadIdx.x & 63;
    int r = blockIdx.x * 4 + w;
    const float4 xv = ((const float4*)(x + (size_t)r * 256))[lane];
    float s = xv.x + xv.y + xv.z + xv.w;
    float s2 = xv.x*xv.x + xv.y*xv.y + xv.z*xv.z + xv.w*xv.w;
    for (int off = 32; off > 0; off >>= 1) {
        s  += __shfl_down(s, off);
        s2 += __shfl_down(s2, off);
    }
    if (lane == 0) {
        float m = s * (1.0f/256.0f);
        float v = s2 * (1.0f/256.0f) - m * m;
        stats[2*r]   = m;
        stats[2*r+1] = rsqrtf(v + LN_EPS);
    }
}

// ---------- K2: pack Wcb[512][256] bf16 : rows 0-255 = Wk, 256-511 = Wv ----------
__global__ __launch_bounds__(256) void pack_wb(const float* __restrict__ Wk,
                                               const float* __restrict__ Wv,
                                               __hip_bfloat16* __restrict__ Wcb) {
    int idx = blockIdx.x * 256 + threadIdx.x;   // 131072 total: n*256 + k
    int n = idx >> 8, k = idx & 255;
    float v = (n < 256) ? Wk[n*256 + k] : Wv[(n-256)*256 + k];
    Wcb[idx] = __float2bfloat16(v);
}

// ---------- K3: fused LN + MFMA GEMM -> k,v (bf16) ----------
// C[131072 x 512] = LN(x) @ Wcb^T ; 128x128 tile, BK=64, 4 waves (2x2)
__global__ __launch_bounds__(256) void gemm_kv_mfma(const float* __restrict__ x,
                                                    const float* __restrict__ stats,
                                                    const float* __restrict__ nx_g,
                                                    const float* __restrict__ nx_b,
                                                    const __hip_bfloat16* __restrict__ Wcb,
                                                    __hip_bfloat16* __restrict__ kp,
                                                    __hip_bfloat16* __restrict__ vp) {
    __shared__ short As[128*64];   // [row][k] bf16 bits
    __shared__ short Bs[128*64];   // [n_local][k]
    const int t = threadIdx.x;
    const int row0 = blockIdx.x * 128;
    const int by = blockIdx.y;
    const int col0 = by * 128;
    const int l = t & 63, wid = t >> 6;
    const int wm = wid >> 1, wn = wid & 1;
    const int lr = l & 15, lk = (l >> 4) * 8;

    f32x4 acc[4][4];
    #pragma unroll
    for (int m = 0; m < 4; ++m)
        #pragma unroll
        for (int n = 0; n < 4; ++n) acc[m][n] = (f32x4){0.f, 0.f, 0.f, 0.f};

    for (int kt = 0; kt < 256; kt += 64) {
        // B tile via global_load_lds (linear LDS, per-lane 16B contiguous global)
        #pragma unroll
        for (int j = 0; j < 4; ++j) {
            int g = j*256 + t;
            const __hip_bfloat16* src = Wcb + (size_t)(col0 + (g >> 3))*256 + kt + (g & 7)*8;
            __builtin_amdgcn_global_load_lds((const __attribute__((address_space(1))) void*)src,
                (__attribute__((address_space(3))) void*)(Bs + g*8), 16, 0, 0);
        }
        // A tile: reg-staged LN(x) -> bf16 -> ds_write_b128
        #pragma unroll
        for (int j = 0; j < 4; ++j) {
            int g = j*256 + t;
            int r = row0 + (g >> 3);
            int c = kt + (g & 7)*8;
            const float4* xs = (const float4*)(x + (size_t)r*256 + c);
            float4 v0 = xs[0], v1 = xs[1];
            float  mm = stats[2*r], rs = stats[2*r+1];
            const float4* gp = (const float4*)(nx_g + c);
            const float4* bp = (const float4*)(nx_b + c);
            float4 g0 = gp[0], g1 = gp[1], b0 = bp[0], b1 = bp[1];
            short8 o;
            o[0] = (short)f2bf((v0.x - mm)*rs*g0.x + b0.x);
            o[1] = (short)f2bf((v0.y - mm)*rs*g0.y + b0.y);
            o[2] = (short)f2bf((v0.z - mm)*rs*g0.z + b0.z);
            o[3] = (short)f2bf((v0.w - mm)*rs*g0.w + b0.w);
            o[4] = (short)f2bf((v1.x - mm)*rs*g1.x + b1.x);
            o[5] = (short)f2bf((v1.y - mm)*rs*g1.y + b1.y);
            o[6] = (short)f2bf((v1.z - mm)*rs*g1.z + b1.z);
            o[7] = (short)f2bf((v1.w - mm)*rs*g1.w + b1.w);
            *(short8*)&As[g*8] = o;
        }
        __syncthreads();   // drains vmcnt (global_load_lds) + lgkmcnt (ds_write)

        #pragma unroll
        for (int kk = 0; kk < 64; kk += 32) {
            short8 af[4], bf[4];
            #pragma unroll
            for (int m = 0; m < 4; ++m)
                af[m] = *(const short8*)&As[(wm*64 + m*16 + lr)*64 + kk + lk];
            #pragma unroll
            for (int n = 0; n < 4; ++n)
                bf[n] = *(const short8*)&Bs[(wn*64 + n*16 + lr)*64 + kk + lk];
            #pragma unroll
            for (int m = 0; m < 4; ++m)
                #pragma unroll
                for (int n = 0; n < 4; ++n)
                    acc[m][n] = __builtin_amdgcn_mfma_f32_16x16x32_bf16(af[m], bf[n], acc[m][n], 0, 0, 0);
        }
        __syncthreads();
    }

    // C write: row=(lane>>4)*4+reg, col=lane&15 (m89-verified layout)
    __hip_bfloat16* dst = (by < 2) ? kp : vp;
    const int colloc = col0 - ((by >= 2) ? 256 : 0);
    #pragma unroll
    for (int m = 0; m < 4; ++m)
        #pragma unroll
        for (int n = 0; n < 4; ++n) {
            #pragma unroll
            for (int jj = 0; jj < 4; ++jj) {
                int r = row0 + wm*64 + m*16 + (l >> 4)*4 + jj;
                int cc = colloc + wn*64 + n*16 + (l & 15);
                dst[(size_t)r*256 + cc] = __float2bfloat16(acc[m][n][jj]);
            }
        }
}

// ---------- K4: slots init ----------
__global__ __launch_bounds__(256) void slots_init(const float* __restrict__ noise,
                                                  const float* __restrict__ mu,
                                                  const float* __restrict__ logsigma,
                                                  float* __restrict__ slots) {
    int i = blockIdx.x * 256 + threadIdx.x;   // 65536
    int d = i & 255;
    slots[i] = mu[d] + expf(logsigma[d]) * noise[i];
}

// ---------- K5: LN(slots) + q projection (one block per slot-row) ----------
__global__ __launch_bounds__(256) void qproj(const float* __restrict__ slots,
                                             const float* __restrict__ ns_g,
                                             const float* __restrict__ ns_b,
                                             const float* __restrict__ Wq,
                                             float* __restrict__ q) {
    int row = blockIdx.x, t = threadIdx.x;
    __shared__ float sn[256];
    __shared__ float red[8];
    float v = slots[row*256 + t];
    float s = v, s2 = v*v;
    for (int off = 32; off > 0; off >>= 1) {
        s  += __shfl_down(s, off);
        s2 += __shfl_down(s2, off);
    }
    if ((t & 63) == 0) { red[t>>6] = s; red[4 + (t>>6)] = s2; }
    __syncthreads();
    float S  = red[0]+red[1]+red[2]+red[3];
    float S2 = red[4]+red[5]+red[6]+red[7];
    float m = S * (1.0f/256.0f);
    float var = S2 * (1.0f/256.0f) - m*m;
    float rs = rsqrtf(var + LN_EPS);
    sn[t] = (v - m) * rs * ns_g[t] + ns_b[t];
    __syncthreads();
    float acc = 0.0f;
    const float4* wrow = (const float4*)(Wq + t*256);
    #pragma unroll 8
    for (int i = 0; i < 64; ++i) {
        float4 w = wrow[i];
        acc += w.x*sn[4*i] + w.y*sn[4*i+1] + w.z*sn[4*i+2] + w.w*sn[4*i+3];
    }
    q[row*256 + t] = acc;
}

// ---------- K6: logits + softmax(K) + attn out + partial updates ----------
__global__ __launch_bounds__(256) void attn_updates(const __hip_bfloat16* __restrict__ kp,
                                                    const __hip_bfloat16* __restrict__ vp,
                                                    const float* __restrict__ q,
                                                    float* __restrict__ attn_out,
                                                    float* __restrict__ partial) {
    int b = blockIdx.x >> 4, ch = blockIdx.x & 15, t = threadIdx.x;
    __shared__ float qs[8][256];
    __shared__ float as[8][256];
    #pragma unroll
    for (int j = 0; j < 8; ++j) qs[j][t] = q[(b*8 + j)*256 + t];
    __syncthreads();

    int n = ch*256 + t;
    const uint4* k4 = (const uint4*)(kp + ((size_t)b*4096 + n)*256);
    float lg[8] = {0,0,0,0,0,0,0,0};
    for (int i = 0; i < 32; ++i) {
        uint4 u = k4[i];
        float f[8];
        bf2x(u.x, f[0], f[1]); bf2x(u.y, f[2], f[3]);
        bf2x(u.z, f[4], f[5]); bf2x(u.w, f[6], f[7]);
        int d0 = i*8;
        #pragma unroll
        for (int kk = 0; kk < 8; ++kk) {
            float a = 0.0f;
            #pragma unroll
            for (int j = 0; j < 8; ++j) a += f[j] * qs[kk][d0 + j];
            lg[kk] += a;
        }
    }
    float mx = -1e30f;
    #pragma unroll
    for (int kk = 0; kk < 8; ++kk) { lg[kk] *= SCALE; mx = fmaxf(mx, lg[kk]); }
    float sum = 0.0f;
    #pragma unroll
    for (int kk = 0; kk < 8; ++kk) { lg[kk] = expf(lg[kk] - mx); sum += lg[kk]; }
    float inv = 1.0f / sum;
    const float renorm = 1.0f / (1.0f + 8.0f*EPSA);
    #pragma unroll
    for (int kk = 0; kk < 8; ++kk) {
        float a = (lg[kk]*inv + EPSA) * renorm;
        as[kk][t] = a;
        attn_out[((size_t)(b*8 + kk))*4096 + n] = a;
    }
    __syncthreads();

    int kk = t >> 5, dg = t & 31;
    float acc[8] = {0,0,0,0,0,0,0,0};
    const uint4* v4 = (const uint4*)(vp + ((size_t)b*4096 + ch*256)*256);
    #pragma unroll 4
    for (int nn = 0; nn < 256; ++nn) {
        float a = as[kk][nn];
        uint4 u = v4[nn*32 + dg];
        float f[8];
        bf2x(u.x, f[0], f[1]); bf2x(u.y, f[2], f[3]);
        bf2x(u.z, f[4], f[5]); bf2x(u.w, f[6], f[7]);
        #pragma unroll
        for (int j = 0; j < 8; ++j) acc[j] += a * f[j];
    }
    float* p = partial + (((size_t)(b*16 + ch)*8 + kk)*256) + dg*8;
    #pragma unroll
    for (int j = 0; j < 8; ++j) p[j] = acc[j];
}

// ---------- K7: reduce partials + GRU cell -> hprime ----------
__global__ __launch_bounds__(256) void gru(const float* __restrict__ partial,
                                           const float* __restrict__ slots,
                                           const float* __restrict__ W_ih,
                                           const float* __restrict__ W_hh,
                                           const float* __restrict__ b_ih,
                                           const float* __restrict__ b_hh,
                                           float* __restrict__ hprime) {
    int r = blockIdx.x, t = threadIdx.x;
    int b = r >> 3, k = r & 7;
    __shared__ float u_s[256], h_s[256];
    float u = 0.0f;
    #pragma unroll
    for (int ch = 0; ch < 16; ++ch)
        u += partial[(((size_t)(b*16 + ch)*8 + k)*256) + t];
    u_s[t] = u;
    h_s[t] = slots[r*256 + t];
    __syncthreads();

    float gi_r = b_ih[t], gi_z = b_ih[256 + t], gi_n = b_ih[512 + t];
    float gh_r = b_hh[t], gh_z = b_hh[256 + t], gh_n = b_hh[512 + t];
    const float4* wir = (const float4*)(W_ih + (size_t)t*256);
    const float4* wiz = (const float4*)(W_ih + (size_t)(256 + t)*256);
    const float4* win = (const float4*)(W_ih + (size_t)(512 + t)*256);
    const float4* whr = (const float4*)(W_hh + (size_t)t*256);
    const float4* whz = (const float4*)(W_hh + (size_t)(256 + t)*256);
    const float4* whn = (const float4*)(W_hh + (size_t)(512 + t)*256);
    #pragma unroll 4
    for (int i = 0; i < 64; ++i) {
        float u0 = u_s[4*i], u1 = u_s[4*i+1], u2 = u_s[4*i+2], u3 = u_s[4*i+3];
        float h0 = h_s[4*i], h1 = h_s[4*i+1], h2 = h_s[4*i+2], h3 = h_s[4*i+3];
        float4 w;
        w = wir[i]; gi_r += w.x*u0 + w.y*u1 + w.z*u2 + w.w*u3;
        w = wiz[i]; gi_z += w.x*u0 + w.y*u1 + w.z*u2 + w.w*u3;
        w = win[i]; gi_n += w.x*u0 + w.y*u1 + w.z*u2 + w.w*u3;
        w = whr[i]; gh_r += w.x*h0 + w.y*h1 + w.z*h2 + w.w*h3;
        w = whz[i]; gh_z += w.x*h0 + w.y*h1 + w.z*h2 + w.w*h3;
        w = whn[i]; gh_n += w.x*h0 + w.y*h1 + w.z*h2 + w.w*h3;
    }
    float rg = sigmoidf_(gi_r + gh_r);
    float zg = sigmoidf_(gi_z + gh_z);
    float ng = tanhf(gi_n + rg * gh_n);
    hprime[r*256 + t] = (1.0f - zg)*ng + zg*h_s[t];
}

// ---------- K8: LN + MLP (GELU exact) + residual -> slots ----------
__global__ __launch_bounds__(256) void mlp(const float* __restrict__ hprime,
                                           const float* __restrict__ mlp_g,
                                           const float* __restrict__ mlp_b,
                                           const float* __restrict__ W1,
                                           const float* __restrict__ b1,
                                           const float* __restrict__ W2,
                                           const float* __restrict__ b2,
                                           float* __restrict__ slots,
                                           float* __restrict__ out_slots,
                                           int last) {
    int r = blockIdx.x, t = threadIdx.x;
    __shared__ float hn[256];
    __shared__ float m1[512];
    __shared__ float red[8];
    float h = hprime[r*256 + t];
    float s = h, s2 = h*h;
    for (int off = 32; off > 0; off >>= 1) {
        s  += __shfl_down(s, off);
        s2 += __shfl_down(s2, off);
    }
    if ((t & 63) == 0) { red[t>>6] = s; red[4 + (t>>6)] = s2; }
    __syncthreads();
    float S  = red[0]+red[1]+red[2]+red[3];
    float S2 = red[4]+red[5]+red[6]+red[7];
    float m = S * (1.0f/256.0f);
    float var = S2 * (1.0f/256.0f) - m*m;
    float rs = rsqrtf(var + LN_EPS);
    hn[t] = (h - m) * rs * mlp_g[t] + mlp_b[t];
    __syncthreads();

    #pragma unroll
    for (int jj = 0; jj < 2; ++jj) {
        int j = t + jj*256;
        float acc = b1[j];
        const float4* w = (const float4*)(W1 + (size_t)j*256);
        #pragma unroll 8
        for (int i = 0; i < 64; ++i) {
            float4 wv = w[i];
            acc += wv.x*hn[4*i] + wv.y*hn[4*i+1] + wv.z*hn[4*i+2] + wv.w*hn[4*i+3];
        }
        m1[j] = 0.5f * acc * (1.0f + erff(acc * 0.70710678118654752f));
    }
    __syncthreads();

    float acc = b2[t];
    const float4* w2 = (const float4*)(W2 + (size_t)t*512);
    #pragma unroll 8
    for (int i = 0; i < 128; ++i) {
        float4 wv = w2[i];
        acc += wv.x*m1[4*i] + wv.y*m1[4*i+1] + wv.z*m1[4*i+2] + wv.w*m1[4*i+3];
    }
    float res = h + acc;
    slots[r*256 + t] = res;
    if (last) out_slots[r*256 + t] = res;
}

// ---------- launch ----------
extern "C" void kernel_launch(void* const* d_in, const int* in_sizes, int n_in,
                              void* d_out, int out_size, void* d_ws, size_t ws_size,
                              hipStream_t stream) {
    const float* x        = (const float*)d_in[0];
    const float* noise    = (const float*)d_in[1];
    const float* nx_g     = (const float*)d_in[2];
    const float* nx_b     = (const float*)d_in[3];
    const float* ns_g     = (const float*)d_in[4];
    const float* ns_b     = (const float*)d_in[5];
    const float* mu       = (const float*)d_in[6];
    const float* logsigma = (const float*)d_in[7];
    const float* Wq       = (const float*)d_in[8];
    const float* Wk       = (const float*)d_in[9];
    const float* Wv       = (const float*)d_in[10];
    const float* W_ih     = (const float*)d_in[11];
    const float* W_hh     = (const float*)d_in[12];
    const float* b_ih     = (const float*)d_in[13];
    const float* b_hh     = (const float*)d_in[14];
    const float* mlp_g    = (const float*)d_in[15];
    const float* mlp_b    = (const float*)d_in[16];
    const float* W1       = (const float*)d_in[17];
    const float* b1       = (const float*)d_in[18];
    const float* W2       = (const float*)d_in[19];
    const float* b2       = (const float*)d_in[20];

    float* out_slots = (float*)d_out;            // [32][8][256]
    float* out_attn  = (float*)d_out + 65536;    // [32][8][4096]

    char* ws = (char*)d_ws;
    float* stats = (float*)ws;                                   // 1 MB
    __hip_bfloat16* Wcb = (__hip_bfloat16*)(stats + 262144);     // 256 KB
    __hip_bfloat16* kp  = Wcb + 131072;                          // 67 MB
    __hip_bfloat16* vp  = kp + (size_t)33554432;                 // 67 MB
    float* slots  = (float*)(vp + (size_t)33554432);             // 256 KB
    float* qbuf   = slots + 65536;                               // 256 KB
    float* partial= qbuf + 65536;                                // 4 MB
    float* hprime = partial + 1048576;                           // 256 KB

    row_stats<<<32768, 256, 0, stream>>>(x, stats);
    pack_wb<<<512, 256, 0, stream>>>(Wk, Wv, Wcb);
    dim3 g2(1024, 4);
    gemm_kv_mfma<<<g2, 256, 0, stream>>>(x, stats, nx_g, nx_b, Wcb, kp, vp);
    slots_init<<<256, 256, 0, stream>>>(noise, mu, logsigma, slots);

    for (int it = 0; it < 3; ++it) {
        qproj<<<256, 256, 0, stream>>>(slots, ns_g, ns_b, Wq, qbuf);
        attn_updates<<<512, 256, 0, stream>>>(kp, vp, qbuf, out_attn, partial);
        gru<<<256, 256, 0, stream>>>(partial, slots, W_ih, W_hh, b_ih, b_hh, hprime);
        mlp<<<256, 256, 0, stream>>>(hprime, mlp_g, mlp_b, W1, b1, W2, b2,
                                     slots, out_slots, it == 2);
    }
}